// Round 6
// baseline (492.076 us; speedup 1.0000x reference)
//
#include <hip/hip_runtime.h>
#include <hip/hip_bf16.h>
#include <stdint.h>

// ---------------------------------------------------------------------------
// SelfAttention QKV projection + head-indexed RoPE, MI355X (gfx950)
//   q = rope(x @ Wq), k = rope(x @ Wk), v = x @ Wv   (pos = head index!)
// Round 6: 32x32x16 MFMA (faster FLOP/cycle, m06/m119) + frag-major LDS
//   layout (all ds_reads are base+lane*16, contiguous 1KB/wave, zero
//   swizzle). Schedule/staging identical to r5's proven 8-phase:
//   A(t+1) staged ph0/1, B(t+2) staged ph2/3, vmcnt(4) gate per tile.
// ---------------------------------------------------------------------------

typedef __attribute__((ext_vector_type(8)))  short short8;
typedef __attribute__((ext_vector_type(4)))  float f32x4;
typedef __attribute__((ext_vector_type(16))) float f32x16;

__device__ __forceinline__ unsigned short f2bf(float f) {
  __bf16 h = (__bf16)f;
  return __builtin_bit_cast(unsigned short, h);
}

__device__ __forceinline__ void gload_lds16(const void* g, void* l) {
  __builtin_amdgcn_global_load_lds((const __attribute__((address_space(1))) void*)g,
                                   (__attribute__((address_space(3))) void*)l,
                                   16, 0, 0);
}

// ---------------- prep kernels ----------------

__global__ __launch_bounds__(256) void convert_x(const float* __restrict__ X,
                                                 unsigned short* __restrict__ Xb,
                                                 int n8) {
  const int stride = gridDim.x * blockDim.x;
  for (int i = blockIdx.x * blockDim.x + threadIdx.x; i < n8; i += stride) {
    const float4 v0 = ((const float4*)X)[(size_t)i * 2 + 0];
    const float4 v1 = ((const float4*)X)[(size_t)i * 2 + 1];
    uint4 w;
    w.x = (uint32_t)f2bf(v0.x) | ((uint32_t)f2bf(v0.y) << 16);
    w.y = (uint32_t)f2bf(v0.z) | ((uint32_t)f2bf(v0.w) << 16);
    w.z = (uint32_t)f2bf(v1.x) | ((uint32_t)f2bf(v1.y) << 16);
    w.w = (uint32_t)f2bf(v1.z) | ((uint32_t)f2bf(v1.w) << 16);
    ((uint4*)Xb)[i] = w;
  }
}

// W (2048x2048 f32, K x N) -> WT (bf16, N x K); z selects which W.
__global__ __launch_bounds__(256) void transpose_cvt3(const float* __restrict__ W0,
                                                      const float* __restrict__ W1,
                                                      const float* __restrict__ W2,
                                                      unsigned short* __restrict__ WT) {
  __shared__ unsigned short tile[64][65];
  const int z = blockIdx.z;
  const float* W = (z == 0) ? W0 : (z == 1) ? W1 : W2;
  unsigned short* WTz = WT + (size_t)z * 2048 * 2048;
  const int bx = blockIdx.x * 64;             // N origin
  const int by = blockIdx.y * 64;             // K origin
  const int t  = threadIdx.x;
  const int tr = t >> 4;
  const int tc = (t & 15) * 4;
#pragma unroll
  for (int i = 0; i < 4; ++i) {
    const int r = tr + i * 16;
    const float4 v = *(const float4*)&W[(size_t)(by + r) * 2048 + bx + tc];
    tile[r][tc + 0] = f2bf(v.x);
    tile[r][tc + 1] = f2bf(v.y);
    tile[r][tc + 2] = f2bf(v.z);
    tile[r][tc + 3] = f2bf(v.w);
  }
  __syncthreads();
#pragma unroll
  for (int i = 0; i < 4; ++i) {
    const int a = tr + i * 16;
    ushort4 o;
    o.x = tile[tc + 0][a];
    o.y = tile[tc + 1][a];
    o.z = tile[tc + 2][a];
    o.w = tile[tc + 3][a];
    *(ushort4*)&WTz[(size_t)(bx + a) * 2048 + by + tc] = o;
  }
}

// ---------------- fused 256x256 GEMM, BK=64, 32x32x16 MFMA -----------------
// LDS frag-major layout per buffer: A at +0, B at +32768, each 32 KiB:
//   offset = blk*4096 + kg*512 + row*16   (blk: 8 x 32-row/col blocks,
//   kg: 8 x 8-k-elem groups, row: 0..31). Frag read for (blk, ks) is
//   base + blk*4096 + ks*1024 + lane*16 — contiguous 1KB/wave, conflict-free.
//   Staging: thread t chunk ch writes LDS ch*8192 + t*16 from global row
//   ch*64 + (t>>8)*32 + (t&31), k-offset ((t>>5)&7)*8. No swizzle anywhere.
// A-operand mapping (32x32x16 bf16): row = lane&31, k = (lane>>5)*8 + b.
// C/D mapping: col = lane&31, row = (reg&3) + 8*(reg>>2) + 4*(lane>>5).

__global__ __launch_bounds__(512, 2) void qkv_fused11(const unsigned short* __restrict__ Xb,
                                                      const unsigned short* __restrict__ WT,
                                                      float* __restrict__ Out) {
  extern __shared__ char smem[];

  // XCD-aware swizzle (1536 blocks, 1536 % 8 == 0 -> bijective)
  const int wg  = blockIdx.x;
  const int swz = (wg & 7) * 192 + (wg >> 3);
  const int mb  = swz / 24, nb = swz % 24;
  const int m0  = mb * 256, n0 = nb * 256;

  const int tid  = threadIdx.x;
  const int wave = tid >> 6, lane = tid & 63;
  const int l31  = lane & 31;
  const int wm   = (wave >> 2) * 128;          // wave row offset (2 M-groups)
  const int wn   = (wave & 3) * 64;            // wave col offset (4 N-groups)
  const int am   = (wave >> 2) * 4;            // first A-blk index for wave
  const int bn   = (wave & 3) * 2;             // first B-blk index for wave

  const unsigned short* Xp = Xb + (size_t)m0 * 2048;
  const unsigned short* Wp = WT + (size_t)n0 * 2048;

  // staging decode for thread t, chunk ch (4 chunks per operand per tile)
  const int sg_rowb = ((tid >> 8) << 5) + (tid & 31);   // + ch*64 = global row
  const int sg_koff = ((tid >> 5) & 7) * 8;             // k element offset

  f32x16 acc[4][2] = {};   // [mblk][nblk]

#define GLD_A(TP, P)                                                          \
  do {                                                                        \
    char* dst_ = smem + (((TP) & 1) << 16);                                   \
    _Pragma("unroll") for (int i_ = 0; i_ < 2; ++i_) {                        \
      const int ch_ = 2 * (P) + i_;                                           \
      gload_lds16(Xp + (size_t)(ch_ * 64 + sg_rowb) * 2048 + (TP) * 64 +      \
                      sg_koff,                                                \
                  dst_ + ch_ * 8192 + tid * 16);                              \
    }                                                                         \
  } while (0)

#define GLD_B(TP, P)                                                          \
  do {                                                                        \
    char* dst_ = smem + (((TP) & 1) << 16) + 32768;                           \
    _Pragma("unroll") for (int i_ = 0; i_ < 2; ++i_) {                        \
      const int ch_ = 2 * (P) + i_;                                           \
      gload_lds16(Wp + (size_t)(ch_ * 64 + sg_rowb) * 2048 + (TP) * 64 +      \
                      sg_koff,                                                \
                  dst_ + ch_ * 8192 + tid * 16);                              \
    }                                                                         \
  } while (0)

#define LDA4(KS)                                                              \
  _Pragma("unroll") for (int m_ = 0; m_ < 4; ++m_)                            \
      af[m_] = *(const short8*)(Ab + (am + m_) * 4096 + (KS) * 1024 +         \
                                lane * 16);

#define PHASE_SYNC                                                            \
  __builtin_amdgcn_s_barrier();                                               \
  asm volatile("s_waitcnt lgkmcnt(0)" ::: "memory");                          \
  __builtin_amdgcn_sched_barrier(0);

#define MFMA8(KS)                                                             \
  do {                                                                        \
    __builtin_amdgcn_s_setprio(1);                                            \
    _Pragma("unroll") for (int m_ = 0; m_ < 4; ++m_)                          \
      _Pragma("unroll") for (int n_ = 0; n_ < 2; ++n_)                        \
        asm("v_mfma_f32_32x32x16_bf16 %0, %1, %2, %0"                         \
            : "+v"(acc[m_][n_])                                               \
            : "v"(af[m_]), "v"(bfr[n_][KS]));                                 \
    __builtin_amdgcn_s_setprio(0);                                            \
  } while (0)

  // prologue: A(0), B(0), B(1); gate leaves B(1)'s 4 loads in flight
  GLD_A(0, 0); GLD_A(0, 1);
  GLD_B(0, 0); GLD_B(0, 1);
  GLD_B(1, 0); GLD_B(1, 1);
  asm volatile("s_waitcnt vmcnt(4)" ::: "memory");
  __builtin_amdgcn_s_barrier();

  for (int t = 0; t < 32; ++t) {
    const char* Ab = smem + ((t & 1) << 16);
    const char* Bb = Ab + 32768;
    short8 bfr[2][4], af[4];

    // ----- ph0: all B frags + A(ks0); stage A(t+1) chunks 0,1 -----
#pragma unroll
    for (int n_ = 0; n_ < 2; ++n_)
#pragma unroll
      for (int ks_ = 0; ks_ < 4; ++ks_)
        bfr[n_][ks_] = *(const short8*)(Bb + (bn + n_) * 4096 + ks_ * 1024 +
                                        lane * 16);
    LDA4(0);
    if (t < 31) GLD_A(t + 1, 0);
    PHASE_SYNC;
    MFMA8(0);
    __builtin_amdgcn_s_barrier();

    // ----- ph1: A(ks1); stage A(t+1) chunks 2,3 -----
    LDA4(1);
    if (t < 31) GLD_A(t + 1, 1);
    PHASE_SYNC;
    MFMA8(1);
    __builtin_amdgcn_s_barrier();

    // ----- ph2: A(ks2); stage B(t+2) chunks 0,1 -----
    LDA4(2);
    if (t < 30) GLD_B(t + 2, 0);
    PHASE_SYNC;
    MFMA8(2);
    __builtin_amdgcn_s_barrier();

    // ----- ph3: A(ks3); stage B(t+2) chunks 2,3; tile-end gate -----
    LDA4(3);
    if (t < 30) GLD_B(t + 2, 1);
    PHASE_SYNC;
    MFMA8(3);
    if (t == 30)     asm volatile("s_waitcnt vmcnt(0)" ::: "memory");
    else if (t < 30) asm volatile("s_waitcnt vmcnt(4)" ::: "memory");
    __builtin_amdgcn_s_barrier();
  }

#undef GLD_A
#undef GLD_B
#undef LDA4
#undef PHASE_SYNC
#undef MFMA8

  // epilogue: fused RoPE. 32x32 C layout: col=lane&31,
  // row = (reg&3) + 8*(reg>>2) + 4*(lane>>5). Partner column = lane^1.
#pragma unroll
  for (int n_ = 0; n_ < 2; ++n_) {
    const int col = n0 + wn + n_ * 32 + l31;
    const int sec = col >> 11;                 // 0=q,1=k,2=v
    const int lc  = col & 2047;
    float c = 1.0f, ssg = 0.0f;
    if (sec < 2) {
      const int h = lc >> 7;
      const int p = (lc & 127) >> 1;
      const float theta = exp2f(-(float)p * 0.20762050593046014f); // log2(1e4)/64
      float s;
      sincosf((float)h * theta, &s, &c);
      ssg = (l31 & 1) ? s : -s;
    }
    float* outp = Out + (size_t)sec * 33554432 + lc;
    const int rbase = m0 + wm + 4 * (lane >> 5);
#pragma unroll
    for (int m_ = 0; m_ < 4; ++m_) {
      const f32x16 a = acc[m_][n_];
#pragma unroll
      for (int r = 0; r < 16; ++r) {
        const int row = rbase + m_ * 32 + (r & 3) + 8 * (r >> 2);
        const float val = a[r];
        float res = val;
        if (sec < 2) {
          const float other = __shfl_xor(val, 1);
          res = val * c + other * ssg;
        }
        __builtin_nontemporal_store(res, outp + (size_t)row * 2048);
      }
    }
  }
}

// ---------------- fallback GEMM (ws too small) ----------------
__global__ __launch_bounds__(256) void qkv_gemm_small(const float* __restrict__ X,
                                                      const unsigned short* __restrict__ WTl,
                                                      float* __restrict__ Out,
                                                      const int do_rope) {
  __shared__ unsigned short As[128 * 64];
  __shared__ unsigned short Bs[128 * 64];
  const int t    = threadIdx.x;
  const int wave = t >> 6, lane = t & 63;
  const int l15  = lane & 15, lg = lane >> 4;
  const int wm   = (wave >> 1) * 64;
  const int wn   = (wave & 1) * 64;
  const int m0   = blockIdx.y * 128;
  const int n0   = blockIdx.x * 128;

  f32x4 acc[4][4] = {};

  for (int kt = 0; kt < 2048; kt += 64) {
#pragma unroll
    for (int i = 0; i < 8; ++i) {
      const int f = i * 256 + t;
      const int row = f >> 4, chunk = f & 15;
      const float4 v = *(const float4*)&X[(size_t)(m0 + row) * 2048 + kt + chunk * 4];
      const uint32_t lo = (uint32_t)f2bf(v.x) | ((uint32_t)f2bf(v.y) << 16);
      const uint32_t hi = (uint32_t)f2bf(v.z) | ((uint32_t)f2bf(v.w) << 16);
      const int slot = chunk >> 1;
      const int off  = row * 128 + (((slot ^ (row & 7)) << 4) | ((chunk & 1) << 3));
      uint2* p = (uint2*)((char*)As + off);
      p->x = lo; p->y = hi;
    }
#pragma unroll
    for (int i = 0; i < 4; ++i) {
      const int seg = i * 4 + wave;
      const int row = seg * 8 + (lane >> 3);
      const int ps  = lane & 7;
      const int ss  = ps ^ (row & 7);
      gload_lds16(WTl + (size_t)(n0 + row) * 2048 + kt + ss * 8,
                  (char*)Bs + seg * 1024 + lane * 16);
    }
    __syncthreads();
#pragma unroll
    for (int kk = 0; kk < 2; ++kk) {
      short8 afr[4], bfr[4];
#pragma unroll
      for (int mi = 0; mi < 4; ++mi) {
        const int row  = wm + mi * 16 + l15;
        const int slot = kk * 4 + lg;
        afr[mi] = *(const short8*)((const char*)As + row * 128 + ((slot ^ (row & 7)) << 4));
      }
#pragma unroll
      for (int ni = 0; ni < 4; ++ni) {
        const int row  = wn + ni * 16 + l15;
        const int slot = kk * 4 + lg;
        bfr[ni] = *(const short8*)((const char*)Bs + row * 128 + ((slot ^ (row & 7)) << 4));
      }
#pragma unroll
      for (int mi = 0; mi < 4; ++mi)
#pragma unroll
        for (int ni = 0; ni < 4; ++ni)
          asm("v_mfma_f32_16x16x32_bf16 %0, %1, %2, %0"
              : "+v"(acc[mi][ni])
              : "v"(afr[mi]), "v"(bfr[ni]));
    }
    __syncthreads();
  }

#pragma unroll
  for (int ni = 0; ni < 4; ++ni) {
    const int col = n0 + wn + ni * 16 + l15;
    float c = 1.0f, ssg = 0.0f;
    if (do_rope) {
      const int h = col >> 7;
      const int p = (col & 127) >> 1;
      const float theta = exp2f(-(float)p * 0.20762050593046014f);
      float s;
      sincosf((float)h * theta, &s, &c);
      ssg = (l15 & 1) ? s : -s;
    }
#pragma unroll
    for (int mi = 0; mi < 4; ++mi) {
      const f32x4 a = acc[mi][ni];
#pragma unroll
      for (int r = 0; r < 4; ++r) {
        const float val = a[r];
        float res = val;
        if (do_rope) {
          const float other = __shfl_xor(val, 1);
          res = val * c + other * ssg;
        }
        Out[(size_t)(m0 + wm + mi * 16 + lg * 4 + r) * 2048 + col] = res;
      }
    }
  }
}

extern "C" void kernel_launch(void* const* d_in, const int* in_sizes, int n_in,
                              void* d_out, int out_size, void* d_ws, size_t ws_size,
                              hipStream_t stream) {
  (void)in_sizes; (void)n_in; (void)out_size;
  const float* x  = (const float*)d_in[0];
  const float* Wq = (const float*)d_in[1];
  const float* Wk = (const float*)d_in[2];
  const float* Wv = (const float*)d_in[3];
  float* out = (float*)d_out;

  const size_t XB_ELEMS = 16384ull * 2048;
  const size_t WT_ELEMS = 6144ull * 2048;

  if (ws_size >= (XB_ELEMS + WT_ELEMS) * sizeof(unsigned short)) {
    unsigned short* Xb  = (unsigned short*)d_ws;
    unsigned short* WTf = Xb + XB_ELEMS;
    convert_x<<<2048, 256, 0, stream>>>(x, Xb, (int)(XB_ELEMS / 8));
    transpose_cvt3<<<dim3(32, 32, 3), 256, 0, stream>>>(Wq, Wk, Wv, WTf);
    hipFuncSetAttribute((const void*)qkv_fused11,
                        hipFuncAttributeMaxDynamicSharedMemorySize, 131072);
    qkv_fused11<<<1536, 512, 131072, stream>>>(Xb, WTf, out);
  } else {
    unsigned short* WqT = (unsigned short*)d_ws;
    unsigned short* WkT = WqT + 2048ull * 2048;
    unsigned short* WvT = WkT + 2048ull * 2048;
    dim3 tb(256), tg(32, 32);
    transpose_cvt3<<<dim3(32, 32, 1), 256, 0, stream>>>(Wq, Wq, Wq, WqT);
    transpose_cvt3<<<dim3(32, 32, 1), 256, 0, stream>>>(Wk, Wk, Wk, WkT);
    transpose_cvt3<<<dim3(32, 32, 1), 256, 0, stream>>>(Wv, Wv, Wv, WvT);
    dim3 gg(16, 128);
    qkv_gemm_small<<<gg, tb, 0, stream>>>(x, WqT, out,            1);
    qkv_gemm_small<<<gg, tb, 0, stream>>>(x, WkT, out + 33554432, 1);
    qkv_gemm_small<<<gg, tb, 0, stream>>>(x, WvT, out + 67108864, 0);
  }
}

// Round 8
// 436.296 us; speedup vs baseline: 1.1279x; 1.1279x over previous
//
#include <hip/hip_runtime.h>
#include <hip/hip_bf16.h>
#include <stdint.h>

// ---------------------------------------------------------------------------
// SelfAttention QKV projection + head-indexed RoPE, MI355X (gfx950)
//   q = rope(x @ Wq), k = rope(x @ Wk), v = x @ Wv   (pos = head index!)
// Round 8: r7 drift-pipeline with the WAR race FIXED. All B-frag reads at
//   tile top, then lgkmcnt(0)+barrier (so GLD_B(t+2) can never clobber
//   unread B data under drift). 2 barriers/tile, counted vmcnt(4) gate,
//   A-frag reads pipelined under MFMA (compiler-counted lgkm waits).
// ---------------------------------------------------------------------------

typedef __attribute__((ext_vector_type(8))) short short8;
typedef __attribute__((ext_vector_type(4))) float f32x4;

__device__ __forceinline__ unsigned short f2bf(float f) {
  __bf16 h = (__bf16)f;
  return __builtin_bit_cast(unsigned short, h);
}

__device__ __forceinline__ void gload_lds16(const void* g, void* l) {
  __builtin_amdgcn_global_load_lds((const __attribute__((address_space(1))) void*)g,
                                   (__attribute__((address_space(3))) void*)l,
                                   16, 0, 0);
}

// ---------------- prep kernels ----------------

__global__ __launch_bounds__(256) void convert_x(const float* __restrict__ X,
                                                 unsigned short* __restrict__ Xb,
                                                 int n8) {
  const int stride = gridDim.x * blockDim.x;
  for (int i = blockIdx.x * blockDim.x + threadIdx.x; i < n8; i += stride) {
    const float4 v0 = ((const float4*)X)[(size_t)i * 2 + 0];
    const float4 v1 = ((const float4*)X)[(size_t)i * 2 + 1];
    uint4 w;
    w.x = (uint32_t)f2bf(v0.x) | ((uint32_t)f2bf(v0.y) << 16);
    w.y = (uint32_t)f2bf(v0.z) | ((uint32_t)f2bf(v0.w) << 16);
    w.z = (uint32_t)f2bf(v1.x) | ((uint32_t)f2bf(v1.y) << 16);
    w.w = (uint32_t)f2bf(v1.z) | ((uint32_t)f2bf(v1.w) << 16);
    ((uint4*)Xb)[i] = w;
  }
}

// W (2048x2048 f32, K x N) -> WT (bf16, N x K); z selects which W.
__global__ __launch_bounds__(256) void transpose_cvt3(const float* __restrict__ W0,
                                                      const float* __restrict__ W1,
                                                      const float* __restrict__ W2,
                                                      unsigned short* __restrict__ WT) {
  __shared__ unsigned short tile[64][65];
  const int z = blockIdx.z;
  const float* W = (z == 0) ? W0 : (z == 1) ? W1 : W2;
  unsigned short* WTz = WT + (size_t)z * 2048 * 2048;
  const int bx = blockIdx.x * 64;             // N origin
  const int by = blockIdx.y * 64;             // K origin
  const int t  = threadIdx.x;
  const int tr = t >> 4;
  const int tc = (t & 15) * 4;
#pragma unroll
  for (int i = 0; i < 4; ++i) {
    const int r = tr + i * 16;
    const float4 v = *(const float4*)&W[(size_t)(by + r) * 2048 + bx + tc];
    tile[r][tc + 0] = f2bf(v.x);
    tile[r][tc + 1] = f2bf(v.y);
    tile[r][tc + 2] = f2bf(v.z);
    tile[r][tc + 3] = f2bf(v.w);
  }
  __syncthreads();
#pragma unroll
  for (int i = 0; i < 4; ++i) {
    const int a = tr + i * 16;
    ushort4 o;
    o.x = tile[tc + 0][a];
    o.y = tile[tc + 1][a];
    o.z = tile[tc + 2][a];
    o.w = tile[tc + 3][a];
    *(ushort4*)&WTz[(size_t)(bx + a) * 2048 + by + tc] = o;
  }
}

// ---------------- fused 256x256 GEMM, BK=64, drift pipeline ----------------
// LDS: buf b at b*64KiB: A[256][64] then B[256][64] (128B rows).
// Swizzle: 16B slot s_phys = s_log ^ (row&7); frag byte = s0 ^ (kk<<6),
// s0 = (lg ^ (l15&7))<<4. Staged linear-dest + inverse-swizzled source.
// Tile body: {read ALL B frags + first A frags; lgkmcnt(0); barrier} then
// 4 MFMA clusters with A-frag reads for cluster p+1 issued before cluster p
// and stage issues spread 2/phase; tile end: vmcnt(4) gate + barrier.
// WAR safety: GLD_B(t+2) hits current buffer's B region only AFTER the
// mid-barrier (all waves' B reads in registers). GLD_A(t+1) hits the other
// buffer (its reads finished before the previous tile-end barrier).
// RAW safety: vmcnt(4) at tile end leaves only B(t+2)'s 4 loads in flight
// => A(t+1), B(t+1) complete before any wave enters tile t+1.

__global__ __launch_bounds__(512, 2) void qkv_fused13(const unsigned short* __restrict__ Xb,
                                                      const unsigned short* __restrict__ WT,
                                                      float* __restrict__ Out) {
  extern __shared__ char smem[];

  // XCD-aware swizzle (1536 blocks, 1536 % 8 == 0 -> bijective)
  const int wg  = blockIdx.x;
  const int swz = (wg & 7) * 192 + (wg >> 3);
  const int mb  = swz / 24, nb = swz % 24;
  const int m0  = mb * 256, n0 = nb * 256;

  const int tid  = threadIdx.x;
  const int wave = tid >> 6, lane = tid & 63;
  const int l15  = lane & 15, lg = lane >> 4;
  const int wm   = (wave >> 2) * 128;          // 2 wave-rows
  const int wn   = (wave & 3) * 64;            // 4 wave-cols
  const int s0   = ((lg ^ (l15 & 7)) << 4);    // kk0 frag slot; kk1 = s0^64

  const unsigned short* Xp = Xb + (size_t)m0 * 2048;
  const unsigned short* Wp = WT + (size_t)n0 * 2048;

  const int srow  = tid >> 3;                  // 0..63
  const int sslot = tid & 7;                   // physical 16B slot

  f32x4 acc[8][4] = {};

#define GLD_A(TP1, H)                                                         \
  do {                                                                        \
    char* dst_ = smem + (((TP1) & 1) << 16) + ((H) << 14);                    \
    _Pragma("unroll") for (int i_ = 0; i_ < 2; ++i_) {                        \
      const int row_ = (H) * 128 + i_ * 64 + srow;                            \
      gload_lds16(Xp + (size_t)row_ * 2048 + (TP1) * 64 +                     \
                      ((sslot ^ (row_ & 7)) << 3),                            \
                  dst_ + i_ * 8192 + tid * 16);                               \
    }                                                                         \
  } while (0)

#define GLD_B(TP2, H)                                                         \
  do {                                                                        \
    char* dst_ = smem + (((TP2) & 1) << 16) + 32768 + ((H) << 14);            \
    _Pragma("unroll") for (int i_ = 0; i_ < 2; ++i_) {                        \
      const int row_ = (H) * 128 + i_ * 64 + srow;                            \
      gload_lds16(Wp + (size_t)row_ * 2048 + (TP2) * 64 +                     \
                      ((sslot ^ (row_ & 7)) << 3),                            \
                  dst_ + i_ * 8192 + tid * 16);                               \
    }                                                                         \
  } while (0)

#define LDA4(DST, MH, KS)                                                     \
  _Pragma("unroll") for (int mi_ = 0; mi_ < 4; ++mi_)                         \
      (DST)[mi_] = *(const short8*)(Ab +                                      \
          ((wm + (MH) * 64 + mi_ * 16 + l15) << 7) + (s0 ^ ((KS) << 6)));

#define LDB4(DST, KS)                                                         \
  _Pragma("unroll") for (int ni_ = 0; ni_ < 4; ++ni_)                         \
      (DST)[ni_] = *(const short8*)(Bb +                                      \
          ((wn + ni_ * 16 + l15) << 7) + (s0 ^ ((KS) << 6)));

#define MFMA16(MH, AR, BR)                                                    \
  do {                                                                        \
    __builtin_amdgcn_s_setprio(1);                                            \
    _Pragma("unroll") for (int mi_ = 0; mi_ < 4; ++mi_)                       \
      _Pragma("unroll") for (int ni_ = 0; ni_ < 4; ++ni_)                     \
        asm("v_mfma_f32_16x16x32_bf16 %0, %1, %2, %0"                         \
            : "+v"(acc[(MH) * 4 + mi_][ni_])                                  \
            : "v"((AR)[mi_]), "v"((BR)[ni_]));                                \
    __builtin_amdgcn_s_setprio(0);                                            \
  } while (0)

  // prologue: A(0), B(0), B(1); gate leaves B(1)'s 4 loads in flight
  GLD_A(0, 0); GLD_A(0, 1);
  GLD_B(0, 0); GLD_B(0, 1);
  GLD_B(1, 0); GLD_B(1, 1);
  asm volatile("s_waitcnt vmcnt(4)" ::: "memory");
  __builtin_amdgcn_s_barrier();

  for (int t = 0; t < 32; ++t) {
    const char* Ab = smem + ((t & 1) << 16);
    const char* Bb = Ab + 32768;
    short8 a0[4], a1[4], b0[4], b1[4];

    // ----- tile top: ALL B frags + first A frags, then ordering point -----
    LDB4(b0, 0);
    LDB4(b1, 1);
    LDA4(a0, 0, 0);
    asm volatile("s_waitcnt lgkmcnt(0)" ::: "memory");
    __builtin_amdgcn_s_barrier();      // B region of this buffer now reusable
    // ----- ph0: prefetch a1; stage A(t+1) h0; MFMA(mh0,ks0) -----
    LDA4(a1, 1, 0);
    if (t < 31) GLD_A(t + 1, 0);
    MFMA16(0, a0, b0);
    // ----- ph1: prefetch a0(ks1); stage A(t+1) h1 -----
    LDA4(a0, 0, 1);
    if (t < 31) GLD_A(t + 1, 1);
    MFMA16(1, a1, b0);                 // waits a1 (counted lgkm)
    // ----- ph2: prefetch a1(ks1); stage B(t+2) h0 -----
    LDA4(a1, 1, 1);
    if (t < 30) GLD_B(t + 2, 0);
    MFMA16(0, a0, b1);                 // waits a0(ks1)
    // ----- ph3: stage B(t+2) h1 -----
    if (t < 30) GLD_B(t + 2, 1);
    MFMA16(1, a1, b1);                 // waits a1(ks1)
    // ----- tile-end gate + barrier -----
    if (t == 30)     asm volatile("s_waitcnt vmcnt(0)" ::: "memory");
    else if (t < 30) asm volatile("s_waitcnt vmcnt(4)" ::: "memory");
    __builtin_amdgcn_s_barrier();
  }

#undef GLD_A
#undef GLD_B
#undef LDA4
#undef LDB4
#undef MFMA16

  // epilogue: fused RoPE. C layout: col=lane&15, row=(lane>>4)*4+reg.
#pragma unroll
  for (int ni = 0; ni < 4; ++ni) {
    const int col = n0 + wn + ni * 16 + l15;
    const int sec = col >> 11;                 // 0=q,1=k,2=v
    const int lc  = col & 2047;
    float c = 1.0f, ssg = 0.0f;
    if (sec < 2) {
      const int h = lc >> 7;
      const int p = (lc & 127) >> 1;
      const float theta = exp2f(-(float)p * 0.20762050593046014f); // log2(1e4)/64
      float s;
      sincosf((float)h * theta, &s, &c);
      ssg = (l15 & 1) ? s : -s;
    }
    float* outp = Out + (size_t)sec * 33554432 + lc;
#pragma unroll
    for (int mi = 0; mi < 8; ++mi) {
      const f32x4 a = acc[mi][ni];
#pragma unroll
      for (int r = 0; r < 4; ++r) {
        const float val = a[r];
        float res = val;
        if (sec < 2) {
          const float other = __shfl_xor(val, 1);
          res = val * c + other * ssg;
        }
        __builtin_nontemporal_store(
            res, outp + (size_t)(m0 + wm + mi * 16 + lg * 4 + r) * 2048);
      }
    }
  }
}

// ---------------- fallback GEMM (ws too small) ----------------
__global__ __launch_bounds__(256) void qkv_gemm_small(const float* __restrict__ X,
                                                      const unsigned short* __restrict__ WTl,
                                                      float* __restrict__ Out,
                                                      const int do_rope) {
  __shared__ unsigned short As[128 * 64];
  __shared__ unsigned short Bs[128 * 64];
  const int t    = threadIdx.x;
  const int wave = t >> 6, lane = t & 63;
  const int l15  = lane & 15, lg = lane >> 4;
  const int wm   = (wave >> 1) * 64;
  const int wn   = (wave & 1) * 64;
  const int m0   = blockIdx.y * 128;
  const int n0   = blockIdx.x * 128;

  f32x4 acc[4][4] = {};

  for (int kt = 0; kt < 2048; kt += 64) {
#pragma unroll
    for (int i = 0; i < 8; ++i) {
      const int f = i * 256 + t;
      const int row = f >> 4, chunk = f & 15;
      const float4 v = *(const float4*)&X[(size_t)(m0 + row) * 2048 + kt + chunk * 4];
      const uint32_t lo = (uint32_t)f2bf(v.x) | ((uint32_t)f2bf(v.y) << 16);
      const uint32_t hi = (uint32_t)f2bf(v.z) | ((uint32_t)f2bf(v.w) << 16);
      const int slot = chunk >> 1;
      const int off  = row * 128 + (((slot ^ (row & 7)) << 4) | ((chunk & 1) << 3));
      uint2* p = (uint2*)((char*)As + off);
      p->x = lo; p->y = hi;
    }
#pragma unroll
    for (int i = 0; i < 4; ++i) {
      const int seg = i * 4 + wave;
      const int row = seg * 8 + (lane >> 3);
      const int ps  = lane & 7;
      const int ss  = ps ^ (row & 7);
      gload_lds16(WTl + (size_t)(n0 + row) * 2048 + kt + ss * 8,
                  (char*)Bs + seg * 1024 + lane * 16);
    }
    __syncthreads();
#pragma unroll
    for (int kk = 0; kk < 2; ++kk) {
      short8 afr[4], bfr[4];
#pragma unroll
      for (int mi = 0; mi < 4; ++mi) {
        const int row  = wm + mi * 16 + l15;
        const int slot = kk * 4 + lg;
        afr[mi] = *(const short8*)((const char*)As + row * 128 + ((slot ^ (row & 7)) << 4));
      }
#pragma unroll
      for (int ni = 0; ni < 4; ++ni) {
        const int row  = wn + ni * 16 + l15;
        const int slot = kk * 4 + lg;
        bfr[ni] = *(const short8*)((const char*)Bs + row * 128 + ((slot ^ (row & 7)) << 4));
      }
#pragma unroll
      for (int mi = 0; mi < 4; ++mi)
#pragma unroll
        for (int ni = 0; ni < 4; ++ni)
          asm("v_mfma_f32_16x16x32_bf16 %0, %1, %2, %0"
              : "+v"(acc[mi][ni])
              : "v"(afr[mi]), "v"(bfr[ni]));
    }
    __syncthreads();
  }

#pragma unroll
  for (int ni = 0; ni < 4; ++ni) {
    const int col = n0 + wn + ni * 16 + l15;
    float c = 1.0f, ssg = 0.0f;
    if (do_rope) {
      const int h = col >> 7;
      const int p = (col & 127) >> 1;
      const float theta = exp2f(-(float)p * 0.20762050593046014f);
      float s;
      sincosf((float)h * theta, &s, &c);
      ssg = (l15 & 1) ? s : -s;
    }
#pragma unroll
    for (int mi = 0; mi < 4; ++mi) {
      const f32x4 a = acc[mi][ni];
#pragma unroll
      for (int r = 0; r < 4; ++r) {
        const float val = a[r];
        float res = val;
        if (do_rope) {
          const float other = __shfl_xor(val, 1);
          res = val * c + other * ssg;
        }
        Out[(size_t)(m0 + wm + mi * 16 + lg * 4 + r) * 2048 + col] = res;
      }
    }
  }
}

extern "C" void kernel_launch(void* const* d_in, const int* in_sizes, int n_in,
                              void* d_out, int out_size, void* d_ws, size_t ws_size,
                              hipStream_t stream) {
  (void)in_sizes; (void)n_in; (void)out_size;
  const float* x  = (const float*)d_in[0];
  const float* Wq = (const float*)d_in[1];
  const float* Wk = (const float*)d_in[2];
  const float* Wv = (const float*)d_in[3];
  float* out = (float*)d_out;

  const size_t XB_ELEMS = 16384ull * 2048;
  const size_t WT_ELEMS = 6144ull * 2048;

  if (ws_size >= (XB_ELEMS + WT_ELEMS) * sizeof(unsigned short)) {
    unsigned short* Xb  = (unsigned short*)d_ws;
    unsigned short* WTf = Xb + XB_ELEMS;
    convert_x<<<2048, 256, 0, stream>>>(x, Xb, (int)(XB_ELEMS / 8));
    transpose_cvt3<<<dim3(32, 32, 3), 256, 0, stream>>>(Wq, Wk, Wv, WTf);
    hipFuncSetAttribute((const void*)qkv_fused13,
                        hipFuncAttributeMaxDynamicSharedMemorySize, 131072);
    qkv_fused13<<<1536, 512, 131072, stream>>>(Xb, WTf, out);
  } else {
    unsigned short* WqT = (unsigned short*)d_ws;
    unsigned short* WkT = WqT + 2048ull * 2048;
    unsigned short* WvT = WkT + 2048ull * 2048;
    dim3 tb(256), tg(32, 32);
    transpose_cvt3<<<dim3(32, 32, 1), 256, 0, stream>>>(Wq, Wq, Wq, WqT);
    transpose_cvt3<<<dim3(32, 32, 1), 256, 0, stream>>>(Wk, Wk, Wk, WkT);
    transpose_cvt3<<<dim3(32, 32, 1), 256, 0, stream>>>(Wv, Wv, Wv, WvT);
    dim3 gg(16, 128);
    qkv_gemm_small<<<gg, tb, 0, stream>>>(x, WqT, out,            1);
    qkv_gemm_small<<<gg, tb, 0, stream>>>(x, WkT, out + 33554432, 1);
    qkv_gemm_small<<<gg, tb, 0, stream>>>(x, WvT, out + 67108864, 0);
  }
}